// Round 2
// baseline (13401.981 us; speedup 1.0000x reference)
//
#include <hip/hip_runtime.h>
#include <hip/hip_bf16.h>
#include <math.h>

// Problem constants
#define TSTEPS 128
#define BATCH  64
#define NTOK   10000
#define NBK    6
#define BSZ    100
#define NHID   600
#define NBLOCKS 192

// Workspace layout (float offsets). Total ~11.02M floats = 44.1 MB.
#define OFF_S1   0ull                          // 8192*600 : s1[t,b,n*100+d] = (Wq_n · k1)*scale
#define OFF_U    (OFF_S1 + 4915200ull)         // 8192*100 : u[t,b,j] = v1 @ fc_w^T
#define OFF_WQT  (OFF_U + 819200ull)           // 6*128*100
#define OFF_FCT  (OFF_WQT + 76800ull)          // 128*100
#define OFF_MFCT (OFF_FCT + 12800ull)          // 64*100  : mha_fc_w^T [e][j]
#define OFF_MGT  (OFF_MFCT + 6400ull)          // 64*100  : mha_gate_w^T [e][j]
#define OFF_MQT  (OFF_MGT + 6400ull)           // 3*6*64*100 : mha q/k/v weights [mat][n][e][d]
#define OFF_HX   (OFF_MQT + 115200ull)         // 64*600 hidden state
#define OFF_A0   (OFF_HX + 38400ull)           // 64*6
#define OFF_MSK  (OFF_A0 + 384ull)             // 64*6
#define OFF_HNEW (OFF_MSK + 384ull)            // 64*600
#define OFF_QKV  (OFF_HNEW + 38400ull)         // 64*1152
#define OFF_OUT  (OFF_QKV + 73728ull)          // 8192*600 per-step hidden states
#define OFF_SYNC (OFF_OUT + 4915200ull)        // 1 u32 barrier counter

// ---------------------------------------------------------------------------
// Kernel 1: one-time weight transposes + barrier-counter zeroing
// ---------------------------------------------------------------------------
__global__ __launch_bounds__(256) void transpose_kernel(
    const float* __restrict__ inp_wq, const float* __restrict__ inp_fc_w,
    const float* __restrict__ mha_fc_w, const float* __restrict__ mha_gate_w,
    const float* __restrict__ mha_wq, const float* __restrict__ mha_wk,
    const float* __restrict__ mha_wv, float* __restrict__ ws)
{
    if (blockIdx.x == 0 && threadIdx.x == 0)
        *(unsigned*)(ws + OFF_SYNC) = 0u;      // barrier counter reset (runs before scan)
    const float rs = 0.08838834764831845f;     // 1/sqrt(128) folded into wqT
    int total = 76800 + 12800 + 6400 + 6400 + 115200;
    for (int idx = blockIdx.x * 256 + threadIdx.x; idx < total; idx += gridDim.x * 256) {
        int i = idx;
        if (i < 76800) {                       // wqT[n][e][d] = wq[n][d][e] * rs
            int n = i / 12800, r = i % 12800, e = r / 100, d = r % 100;
            ws[OFF_WQT + i] = inp_wq[n * 12800 + d * 128 + e] * rs;
        } else if ((i -= 76800) < 12800) {     // fcT[e][j] = fc_w[j][e]
            int e = i / 100, j = i % 100;
            ws[OFF_FCT + i] = inp_fc_w[j * 128 + e];
        } else if ((i -= 12800) < 6400) {      // mfcT[e][j] = mha_fc_w[j][e]
            int e = i / 100, j = i % 100;
            ws[OFF_MFCT + i] = mha_fc_w[j * 64 + e];
        } else if ((i -= 6400) < 6400) {
            int e = i / 100, j = i % 100;
            ws[OFF_MGT + i] = mha_gate_w[j * 64 + e];
        } else {                               // mqT[o][d], o = mat*384+n*64+e
            i -= 6400;
            int o = i / 100, d = i % 100;
            int mat = o / 384, n = (o % 384) / 64, e = o % 64;
            const float* W = (mat == 0 ? mha_wq : (mat == 1 ? mha_wk : mha_wv));
            ws[OFF_MQT + i] = W[n * 6400 + d * 64 + e];
        }
    }
}

// ---------------------------------------------------------------------------
// Kernel 2: precompute (parallel over t,b):  k1=emb@Wk0, v1=emb@Wv0,
//   u = v1@fc_w^T, s1[n,d] = (Wq[n]·k1)[d]*scale.  16 rows per workgroup.
// ---------------------------------------------------------------------------
__global__ __launch_bounds__(256) void precompute_kernel(
    const int* __restrict__ input, const float* __restrict__ encoder_w,
    const float* __restrict__ inp_wk, const float* __restrict__ inp_wv,
    float* __restrict__ ws)
{
    __shared__ float es[16 * 600];
    __shared__ float k1s[16 * 128];
    __shared__ float v1s[16 * 128];
    __shared__ int   toks[16];
    int tid = threadIdx.x;
    int row0 = blockIdx.x * 16;
    if (tid < 16) toks[tid] = input[row0 + tid];
    __syncthreads();
    for (int i = tid; i < 16 * 600; i += 256) {
        int r = i / 600, d = i % 600;
        es[i] = encoder_w[(size_t)toks[r] * 600 + d];
    }
    __syncthreads();
    {
        int mat = tid >> 7, ii = tid & 127;
        const float* W = (mat == 0 ? inp_wk : inp_wv);
        float acc[16];
#pragma unroll
        for (int r = 0; r < 16; r++) acc[r] = 0.f;
        for (int d = 0; d < 600; d++) {
            float wv = W[d * 128 + ii];
#pragma unroll
            for (int r = 0; r < 16; r++) acc[r] += es[r * 600 + d] * wv;
        }
        float* dst = (mat == 0 ? k1s : v1s);
#pragma unroll
        for (int r = 0; r < 16; r++) dst[r * 128 + ii] = acc[r];
    }
    __syncthreads();
    const float* fcT = ws + OFF_FCT;
    for (int i = tid; i < 16 * 100; i += 256) {
        int r = i / 100, j = i % 100;
        float acc = 0.f;
        for (int e = 0; e < 128; e++) acc += v1s[r * 128 + e] * fcT[e * 100 + j];
        ws[OFF_U + (size_t)(row0 + r) * 100 + j] = acc;
    }
    const float* wqT = ws + OFF_WQT;
    for (int i = tid; i < 16 * 600; i += 256) {
        int r = i / 600, q = i % 600, n = q / 100, d = q % 100;
        float acc = 0.f;
        for (int e = 0; e < 128; e++) acc += k1s[r * 128 + e] * wqT[(n * 128 + e) * 100 + d];
        ws[OFF_S1 + (size_t)(row0 + r) * 600 + q] = acc;
    }
}

// ---------------------------------------------------------------------------
// Kernel 3: weight-stationary cooperative scan. 192 blocks x 512 threads,
// all co-resident (61 KB LDS, 1+/CU). 3 device-wide barriers per step.
//   Phase G (192 blocks): GRU slice (n, 3-4 j-cols), weights LDS-resident.
//   Phase Q (72 blocks):  MHA qkv slice (mat, n, 16 e).
//   Phase B (64 blocks):  per-batch attention + fc/gate + blend + next scores.
// ---------------------------------------------------------------------------
__global__ __launch_bounds__(512) void scan_coop(
    const float* __restrict__ hidden, const float* __restrict__ inp_fc_b,
    const float* __restrict__ mha_fc_b, const float* __restrict__ mha_gate_b,
    const float* __restrict__ gru_w_ih, const float* __restrict__ gru_w_hh,
    const float* __restrict__ gru_b_ih, const float* __restrict__ gru_b_hh,
    float* __restrict__ ws)
{
    __shared__ float smem[12928];   // G: hxs[64*101]+ius[64*101]; Q: hn+qw; B: qs/att/outv/hxn
    __shared__ float gw[2400];      // persistent GRU weight slice [jl][g6][d]
    __shared__ float sml[32];

    int blk = blockIdx.x, tid = threadIdx.x;
    unsigned* syncc = (unsigned*)(ws + OFF_SYNC);
    unsigned bar_target = 0;

    // --- persistent GRU weight slice ---
    int n = blk / 32, s = blk % 32;
    int j0 = (s * 100) / 32, j1 = ((s + 1) * 100) / 32, nj = j1 - j0;
    for (int i = tid; i < nj * 600; i += 512) {
        int jl = i / 600, g6 = (i % 600) / 100, d = i % 100;
        int gg = g6 % 3;
        const float* src = (g6 < 3) ? gru_w_ih : gru_w_hh;
        gw[i] = src[n * 30000 + (gg * 100 + j0 + jl) * 100 + d];
    }

    // --- init: hx, a0/mask for t=0 (blocks 0..63) ---
    if (blk < 64) {
        int b = blk;
        float* hxn = smem + 2048;
        for (int i = tid; i < 600; i += 512) {
            float v = hidden[b * 600 + i];
            hxn[i] = v;
            ws[OFF_HX + b * 600 + i] = v;
        }
        __syncthreads();
        const float* s1t = ws + OFF_S1 + (size_t)b * 600;   // t=0
        int w = tid >> 6, lane = tid & 63;
        if (w < 6) {
            float p = hxn[w * 100 + lane] * s1t[w * 100 + lane];
            if (lane < 36) p += hxn[w * 100 + 64 + lane] * s1t[w * 100 + 64 + lane];
#pragma unroll
            for (int off = 32; off > 0; off >>= 1) p += __shfl_down(p, off, 64);
            if (lane == 0) sml[8 + w] = p;
        }
        __syncthreads();
        if (tid == 0) {
            float a0v[6], sv[6];
            for (int q = 0; q < 6; q++) { a0v[q] = 1.f / (1.f + expf(-sml[8 + q])); sv[q] = a0v[q]; }
            for (int a = 0; a < 5; a++)
                for (int c = a + 1; c < 6; c++)
                    if (sv[c] > sv[a]) { float tm = sv[a]; sv[a] = sv[c]; sv[c] = tm; }
            float kth = sv[3] - 0.01f;
            for (int q = 0; q < 6; q++) {
                ws[OFF_A0 + b * 6 + q] = a0v[q];
                ws[OFF_MSK + b * 6 + q] = (a0v[q] > kth) ? 1.f : 0.f;
            }
        }
    }

    // device-wide barrier helper (counter monotonically increasing)
#define GSYNC() do {                                                              \
        bar_target += NBLOCKS;                                                    \
        __syncthreads();                                                          \
        if (tid == 0) {                                                           \
            __threadfence();                                                      \
            __hip_atomic_fetch_add(syncc, 1u, __ATOMIC_ACQ_REL, __HIP_MEMORY_SCOPE_AGENT); \
            while (__hip_atomic_load(syncc, __ATOMIC_ACQUIRE, __HIP_MEMORY_SCOPE_AGENT) < bar_target) \
                __builtin_amdgcn_s_sleep(1);                                      \
        }                                                                         \
        __syncthreads();                                                          \
    } while (0)

    GSYNC();

    for (int t = 0; t < TSTEPS; t++) {
        // ================= Phase G: GRU (all 192 blocks) =================
        {
            float* hxs = smem;
            float* ius = smem + 6464;
            for (int i = tid; i < 6400; i += 512) {
                int b = i / 100, d = i % 100;
                hxs[b * 101 + d] = ws[OFF_HX + b * 600 + n * 100 + d];
                ius[b * 101 + d] = ws[OFF_A0 + b * 6 + n] *
                                   ws[OFF_U + (size_t)(t * 64 + b) * 100 + d] + inp_fc_b[d];
            }
            __syncthreads();
            int bl = tid & 63, jl = tid >> 6;
            if (jl < nj) {
                int jg = j0 + jl;
                float ax0 = gru_b_ih[n * 300 + jg];
                float ax1 = gru_b_ih[n * 300 + 100 + jg];
                float ax2 = gru_b_ih[n * 300 + 200 + jg];
                float ah0 = gru_b_hh[n * 300 + jg];
                float ah1 = gru_b_hh[n * 300 + 100 + jg];
                float ah2 = gru_b_hh[n * 300 + 200 + jg];
                const float* gwj = gw + jl * 600;
                const float* hb = hxs + bl * 101;
                const float* ib = ius + bl * 101;
#pragma unroll 4
                for (int d = 0; d < 100; d++) {
                    float x = ib[d], h = hb[d];
                    ax0 += x * gwj[d];       ax1 += x * gwj[100 + d]; ax2 += x * gwj[200 + d];
                    ah0 += h * gwj[300 + d]; ah1 += h * gwj[400 + d]; ah2 += h * gwj[500 + d];
                }
                float r = 1.f / (1.f + expf(-(ax0 + ah0)));
                float z = 1.f / (1.f + expf(-(ax1 + ah1)));
                float nn = tanhf(ax2 + r * ah2);
                float hnew = (1.f - z) * nn + z * hb[jg];
                ws[OFF_HNEW + bl * 600 + n * 100 + jg] = hnew;
            }
        }
        GSYNC();

        // ================= Phase Q: MHA qkv (blocks 0..71) =================
        if (blk < 72) {
            int mat = blk / 24, n2 = (blk % 24) / 4, e0 = (blk % 4) * 16;
            float* hn = smem;
            float* qw = smem + 6464;
            for (int i = tid; i < 6400; i += 512) {
                int b = i / 100, d = i % 100;
                hn[b * 101 + d] = ws[OFF_HNEW + b * 600 + n2 * 100 + d];
            }
            for (int i = tid; i < 1600; i += 512) {
                int el = i / 100, d = i % 100;
                qw[el * 100 + d] = ws[OFF_MQT + (size_t)((mat * 6 + n2) * 64 + e0 + el) * 100 + d];
            }
            __syncthreads();
            int bl = tid & 63, eg = tid >> 6;          // eg in [0,8): 2 e's each
            const float* hb = hn + bl * 101;
            const float* w0 = qw + (eg * 2) * 100;
            const float* w1 = w0 + 100;
            float a0_ = 0.f, a1_ = 0.f;
#pragma unroll 4
            for (int d = 0; d < 100; d++) { float h = hb[d]; a0_ += h * w0[d]; a1_ += h * w1[d]; }
            int o = mat * 384 + n2 * 64 + e0 + eg * 2;
            ws[OFF_QKV + bl * 1152 + o]     = a0_;
            ws[OFF_QKV + bl * 1152 + o + 1] = a1_;
        }
        GSYNC();

        // ================= Phase B: per-batch tail (blocks 0..63) =================
        if (blk < 64) {
            int b = blk;
            float* qs   = smem;
            float* attv = smem + 1152;
            float* outv = smem + 1536;
            float* hxn  = smem + 2048;
            for (int i = tid; i < 1152; i += 512) qs[i] = ws[OFF_QKV + b * 1152 + i];
            if (tid < 6) sml[tid] = ws[OFF_MSK + b * 6 + tid];
            __syncthreads();
            if (tid < 144) {
                int h = tid / 36, rem = tid % 36, nq = rem / 6, nk = rem % 6;
                const float* qp = qs + nq * 64 + h * 16;
                const float* kp = qs + 384 + nk * 64 + h * 16;
                float acc = 0.f;
#pragma unroll
                for (int d = 0; d < 16; d++) acc += qp[d] * kp[d];
                attv[tid] = acc * 0.25f;
            }
            __syncthreads();
            if (tid < 24) {
                int base = tid * 6;
                float m = attv[base];
                for (int k2 = 1; k2 < 6; k2++) m = fmaxf(m, attv[base + k2]);
                float ssum = 0.f, ex[6];
                for (int k2 = 0; k2 < 6; k2++) { ex[k2] = expf(attv[base + k2] - m); ssum += ex[k2]; }
                float inv = 1.f / ssum;
                for (int k2 = 0; k2 < 6; k2++) attv[base + k2] = ex[k2] * inv;
            }
            __syncthreads();
            if (tid < 384) {
                int n3 = tid / 64, e = tid % 64, h = e / 16;
                const float* ap = attv + h * 36 + n3 * 6;
                float acc = 0.f;
#pragma unroll
                for (int nk = 0; nk < 6; nk++) acc += ap[nk] * qs[768 + nk * 64 + e];
                outv[tid] = acc;
            }
            __syncthreads();
            for (int i = tid; i < 600; i += 512) {
                int n3 = i / 100, j = i % 100;
                float newv;
                if (sml[n3] != 0.f) {
                    float pj = mha_fc_b[j], gt = mha_gate_b[j];
                    const float* ov = outv + n3 * 64;
                    const float* fT = ws + OFF_MFCT + j;
                    const float* gT = ws + OFF_MGT + j;
#pragma unroll 8
                    for (int e = 0; e < 64; e++) {
                        float o = ov[e];
                        pj += o * fT[e * 100];
                        gt += o * gT[e * 100];
                    }
                    newv = (1.f / (1.f + expf(-gt))) * tanhf(pj);
                } else {
                    newv = ws[OFF_HX + b * 600 + i];
                }
                hxn[i] = newv;
                ws[OFF_HX + b * 600 + i] = newv;
                ws[OFF_OUT + (size_t)(t * 64 + b) * 600 + i] = newv;
            }
            __syncthreads();
            if (t < 127) {
                const float* s1t = ws + OFF_S1 + (size_t)((t + 1) * 64 + b) * 600;
                int w = tid >> 6, lane = tid & 63;
                if (w < 6) {
                    float p = hxn[w * 100 + lane] * s1t[w * 100 + lane];
                    if (lane < 36) p += hxn[w * 100 + 64 + lane] * s1t[w * 100 + 64 + lane];
#pragma unroll
                    for (int off = 32; off > 0; off >>= 1) p += __shfl_down(p, off, 64);
                    if (lane == 0) sml[8 + w] = p;
                }
                __syncthreads();
                if (tid == 0) {
                    float a0v[6], sv[6];
                    for (int q = 0; q < 6; q++) { a0v[q] = 1.f / (1.f + expf(-sml[8 + q])); sv[q] = a0v[q]; }
                    for (int a = 0; a < 5; a++)
                        for (int c = a + 1; c < 6; c++)
                            if (sv[c] > sv[a]) { float tm = sv[a]; sv[a] = sv[c]; sv[c] = tm; }
                    float kth = sv[3] - 0.01f;
                    for (int q = 0; q < 6; q++) {
                        ws[OFF_A0 + b * 6 + q] = a0v[q];
                        ws[OFF_MSK + b * 6 + q] = (a0v[q] > kth) ? 1.f : 0.f;
                    }
                }
            }
        }
        GSYNC();
    }
#undef GSYNC
}

// ---------------------------------------------------------------------------
// Kernel 4: decode GEMM  C(8192x10000) = A(8192x600) @ W^T + b   (fp32)
// ---------------------------------------------------------------------------
__global__ __launch_bounds__(256) void decode_kernel(
    const float* __restrict__ A, const float* __restrict__ W,
    const float* __restrict__ bias, float* __restrict__ C)
{
    __shared__ float As[8][132];
    __shared__ float Bs[8][132];
    int tid = threadIdx.x;
    int m0 = blockIdx.x * 128;
    int n0 = blockIdx.y * 128;
    int tn = tid % 16, tm = tid / 16;
    int lr = tid / 2, lc = tid % 2;

    float acc[8][8];
#pragma unroll
    for (int i = 0; i < 8; i++)
#pragma unroll
        for (int j = 0; j < 8; j++) acc[i][j] = 0.f;

    for (int k0 = 0; k0 < 600; k0 += 8) {
        float4 av = *(const float4*)(A + (size_t)(m0 + lr) * 600 + k0 + lc * 4);
        float4 bv = make_float4(0.f, 0.f, 0.f, 0.f);
        int wrow = n0 + lr;
        if (wrow < NTOK) bv = *(const float4*)(W + (size_t)wrow * 600 + k0 + lc * 4);
        __syncthreads();
        As[lc*4+0][lr] = av.x; As[lc*4+1][lr] = av.y; As[lc*4+2][lr] = av.z; As[lc*4+3][lr] = av.w;
        Bs[lc*4+0][lr] = bv.x; Bs[lc*4+1][lr] = bv.y; Bs[lc*4+2][lr] = bv.z; Bs[lc*4+3][lr] = bv.w;
        __syncthreads();
#pragma unroll
        for (int kk = 0; kk < 8; kk++) {
            float4 x0 = *(const float4*)&As[kk][tm * 8];
            float4 x1 = *(const float4*)&As[kk][tm * 8 + 4];
            float4 y0 = *(const float4*)&Bs[kk][tn * 8];
            float4 y1 = *(const float4*)&Bs[kk][tn * 8 + 4];
            float a8[8] = {x0.x, x0.y, x0.z, x0.w, x1.x, x1.y, x1.z, x1.w};
            float b8[8] = {y0.x, y0.y, y0.z, y0.w, y1.x, y1.y, y1.z, y1.w};
#pragma unroll
            for (int i = 0; i < 8; i++)
#pragma unroll
                for (int j = 0; j < 8; j++) acc[i][j] += a8[i] * b8[j];
        }
    }

    int nbase = n0 + tn * 8;
    if (nbase < NTOK) {
        float4 bb0 = *(const float4*)(bias + nbase);
        float4 bb1 = *(const float4*)(bias + nbase + 4);
#pragma unroll
        for (int i = 0; i < 8; i++) {
            float* crow = C + (size_t)(m0 + tm * 8 + i) * NTOK + nbase;
            float4 s0 = make_float4(acc[i][0]+bb0.x, acc[i][1]+bb0.y, acc[i][2]+bb0.z, acc[i][3]+bb0.w);
            float4 s1v = make_float4(acc[i][4]+bb1.x, acc[i][5]+bb1.y, acc[i][6]+bb1.z, acc[i][7]+bb1.w);
            *(float4*)crow = s0;
            *(float4*)(crow + 4) = s1v;
        }
    }
}

// ---------------------------------------------------------------------------
// Kernel 5: hx_final tail + scalar
// ---------------------------------------------------------------------------
__global__ __launch_bounds__(256) void finalize_kernel(
    const float* __restrict__ outp, float* __restrict__ out)
{
    int idx = blockIdx.x * 256 + threadIdx.x;
    if (idx < 38400) out[81920000u + idx] = outp[(size_t)(127 * 64) * 600 + idx];
    if (idx == 38400) out[81958400u] = 0.0f;
}

// ---------------------------------------------------------------------------
extern "C" void kernel_launch(void* const* d_in, const int* in_sizes, int n_in,
                              void* d_out, int out_size, void* d_ws, size_t ws_size,
                              hipStream_t stream)
{
    const int*   input      = (const int*)  d_in[0];
    const float* hidden     = (const float*)d_in[1];
    const float* encoder_w  = (const float*)d_in[2];
    const float* inp_wq     = (const float*)d_in[3];
    const float* inp_wk     = (const float*)d_in[4];
    const float* inp_wv     = (const float*)d_in[5];
    const float* inp_fc_w   = (const float*)d_in[6];
    const float* inp_fc_b   = (const float*)d_in[7];
    const float* mha_wq     = (const float*)d_in[8];
    const float* mha_wk     = (const float*)d_in[9];
    const float* mha_wv     = (const float*)d_in[10];
    const float* mha_fc_w   = (const float*)d_in[11];
    const float* mha_fc_b   = (const float*)d_in[12];
    const float* mha_gate_w = (const float*)d_in[13];
    const float* mha_gate_b = (const float*)d_in[14];
    const float* gru_w_ih   = (const float*)d_in[15];
    const float* gru_w_hh   = (const float*)d_in[16];
    const float* gru_b_ih   = (const float*)d_in[17];
    const float* gru_b_hh   = (const float*)d_in[18];
    const float* dec_w      = (const float*)d_in[19];
    const float* dec_b      = (const float*)d_in[20];
    float* out = (float*)d_out;
    float* ws  = (float*)d_ws;

    transpose_kernel<<<256, 256, 0, stream>>>(inp_wq, inp_fc_w, mha_fc_w, mha_gate_w,
                                              mha_wq, mha_wk, mha_wv, ws);
    precompute_kernel<<<512, 256, 0, stream>>>(input, encoder_w, inp_wk, inp_wv, ws);
    scan_coop<<<NBLOCKS, 512, 0, stream>>>(hidden, inp_fc_b, mha_fc_b, mha_gate_b,
                                           gru_w_ih, gru_w_hh, gru_b_ih, gru_b_hh, ws);
    decode_kernel<<<dim3(64, 79), dim3(256), 0, stream>>>(ws + OFF_OUT, dec_w, dec_b, out);
    finalize_kernel<<<151, 256, 0, stream>>>(ws + OFF_OUT, out);
}

// Round 3
// 3800.640 us; speedup vs baseline: 3.5262x; 3.5262x over previous
//
#include <hip/hip_runtime.h>
#include <hip/hip_bf16.h>
#include <math.h>

// Problem constants
#define TSTEPS 128
#define BATCH  64
#define NTOK   10000
#define NBK    6
#define BSZ    100
#define NHID   600

// Workspace layout (float offsets). Base (no P): 45.1 MB. With P: 103.9 MB.
#define OFF_S1   0ull                      // 8192*600
#define OFF_U    4915200ull                // 8192*100
#define OFF_WQT  5734400ull                // 6*128*100 (precompute)
#define OFF_FCT  5811200ull                // 128*100   (precompute)
#define OFF_FC4  5824000ull                // 16*100*4  : fc_w  packed [e4][j][4]
#define OFF_GG4  5830400ull                // 16*100*4  : gate_w packed
#define OFF_MQ4  5836800ull                // 25*1152*4 : qkv packed [d4][o][4]
#define OFF_WHH4 5952000ull                // 6*25*300*4: whh packed [n][d4][g][4]
#define OFF_WIH4 6132000ull                // 6*25*300*4: wih packed (fallback)
#define OFF_GXB  6312000ull                // 1800 : wih@fc_b + b_ih
#define OFF_OUT  6313800ull                // 8192*600
#define OFF_P    11229000ull               // 8192*1800 : P[t,b][n*300+g] = wih@u
#define TOTAL_WITH_P (OFF_P + 14745600ull)

// ---------------------------------------------------------------------------
// Kernel 1: one-time weight transposes / float4 packing + GXB
// ---------------------------------------------------------------------------
__global__ __launch_bounds__(256) void transpose_kernel(
    const float* __restrict__ inp_wq, const float* __restrict__ inp_fc_w,
    const float* __restrict__ inp_fc_b,
    const float* __restrict__ mha_fc_w, const float* __restrict__ mha_gate_w,
    const float* __restrict__ mha_wq, const float* __restrict__ mha_wk,
    const float* __restrict__ mha_wv,
    const float* __restrict__ gru_w_ih, const float* __restrict__ gru_w_hh,
    const float* __restrict__ gru_b_ih, float* __restrict__ ws)
{
    const float rs = 0.08838834764831845f; // 1/sqrt(128) folded into wqT
    int total = 76800 + 12800 + 6400 + 6400 + 115200 + 180000 + 180000 + 1800;
    for (int idx = blockIdx.x * 256 + threadIdx.x; idx < total; idx += gridDim.x * 256) {
        int i = idx;
        if (i < 76800) {                       // wqT[n][e][d] = wq[n][d][e] * rs
            int n = i / 12800, r = i % 12800, e = r / 100, d = r % 100;
            ws[OFF_WQT + i] = inp_wq[n * 12800 + d * 128 + e] * rs;
        } else if ((i -= 76800) < 12800) {     // fcT[e][j]
            int e = i / 100, j = i % 100;
            ws[OFF_FCT + i] = inp_fc_w[j * 128 + e];
        } else if ((i -= 12800) < 6400) {      // FC4 [e4][j][4]
            int q = i / 4, c = i % 4, e4 = q / 100, j = q % 100;
            ws[OFF_FC4 + i] = mha_fc_w[j * 64 + e4 * 4 + c];
        } else if ((i -= 6400) < 6400) {       // GG4
            int q = i / 4, c = i % 4, e4 = q / 100, j = q % 100;
            ws[OFF_GG4 + i] = mha_gate_w[j * 64 + e4 * 4 + c];
        } else if ((i -= 6400) < 115200) {     // MQ4 [d4][o][4], o=mat*384+n*64+e
            int q = i / 4, c = i % 4, d4 = q / 1152, o = q % 1152;
            int mat = o / 384, n2 = (o % 384) / 64, e = o % 64, d = d4 * 4 + c;
            const float* W = (mat == 0 ? mha_wq : (mat == 1 ? mha_wk : mha_wv));
            ws[OFF_MQ4 + i] = W[n2 * 6400 + d * 64 + e];
        } else if ((i -= 115200) < 180000) {   // WHH4 [n][d4][g][4]
            int q = i / 4, c = i % 4, n = q / 7500, r2 = q % 7500;
            int d4 = r2 / 300, g = r2 % 300;
            ws[OFF_WHH4 + i] = gru_w_hh[n * 30000 + g * 100 + d4 * 4 + c];
        } else if ((i -= 180000) < 180000) {   // WIH4
            int q = i / 4, c = i % 4, n = q / 7500, r2 = q % 7500;
            int d4 = r2 / 300, g = r2 % 300;
            ws[OFF_WIH4 + i] = gru_w_ih[n * 30000 + g * 100 + d4 * 4 + c];
        } else {                               // GXB[n*300+g] = wih[n,g]·fc_b + b_ih
            i -= 180000;
            int n = i / 300, g = i % 300;
            const float* wr = gru_w_ih + n * 30000 + g * 100;
            float acc = gru_b_ih[n * 300 + g];
            for (int d = 0; d < 100; d++) acc += wr[d] * inp_fc_b[d];
            ws[OFF_GXB + i] = acc;
        }
    }
}

// ---------------------------------------------------------------------------
// Kernel 2: precompute k1/v1/u/s1 (parallel over t,b). 16 rows per block.
// ---------------------------------------------------------------------------
__global__ __launch_bounds__(256) void precompute_kernel(
    const int* __restrict__ input, const float* __restrict__ encoder_w,
    const float* __restrict__ inp_wk, const float* __restrict__ inp_wv,
    float* __restrict__ ws)
{
    __shared__ float es[16 * 600];
    __shared__ float k1s[16 * 128];
    __shared__ float v1s[16 * 128];
    __shared__ int   toks[16];
    int tid = threadIdx.x;
    int row0 = blockIdx.x * 16;
    if (tid < 16) toks[tid] = input[row0 + tid];
    __syncthreads();
    for (int i = tid; i < 16 * 600; i += 256) {
        int r = i / 600, d = i % 600;
        es[i] = encoder_w[(size_t)toks[r] * 600 + d];
    }
    __syncthreads();
    {
        int mat = tid >> 7, ii = tid & 127;
        const float* W = (mat == 0 ? inp_wk : inp_wv);
        float acc[16];
#pragma unroll
        for (int r = 0; r < 16; r++) acc[r] = 0.f;
        for (int d = 0; d < 600; d++) {
            float wv = W[d * 128 + ii];
#pragma unroll
            for (int r = 0; r < 16; r++) acc[r] += es[r * 600 + d] * wv;
        }
        float* dst = (mat == 0 ? k1s : v1s);
#pragma unroll
        for (int r = 0; r < 16; r++) dst[r * 128 + ii] = acc[r];
    }
    __syncthreads();
    const float* fcT = ws + OFF_FCT;
    for (int i = tid; i < 16 * 100; i += 256) {
        int r = i / 100, j = i % 100;
        float acc = 0.f;
        for (int e = 0; e < 128; e++) acc += v1s[r * 128 + e] * fcT[e * 100 + j];
        ws[OFF_U + (size_t)(row0 + r) * 100 + j] = acc;
    }
    const float* wqT = ws + OFF_WQT;
    for (int i = tid; i < 16 * 600; i += 256) {
        int r = i / 600, q = i % 600, n = q / 100, d = q % 100;
        float acc = 0.f;
        for (int e = 0; e < 128; e++) acc += k1s[r * 128 + e] * wqT[(n * 128 + e) * 100 + d];
        ws[OFF_S1 + (size_t)(row0 + r) * 600 + q] = acc;
    }
}

// ---------------------------------------------------------------------------
// Kernel 2b: P[t,b][n*300+g] = wih[n,g,:]·u[t,b,:]  (weight-stationary tiles)
// grid = rg(16) x n(6) x gt(5); block weights 60x100 in LDS; 512 rows each.
// ---------------------------------------------------------------------------
__global__ __launch_bounds__(256) void pgate_kernel(
    const float* __restrict__ gru_w_ih, float* __restrict__ ws)
{
    __shared__ float wsl[60 * 100];
    __shared__ float us[16 * 101];
    int blk = blockIdx.x;
    int rg = blk / 30, rem = blk % 30, n = rem / 5, gt = rem % 5;
    int g0 = gt * 60, tid = threadIdx.x;
    for (int i = tid; i < 6000; i += 256)
        wsl[i] = gru_w_ih[n * 30000 + (g0 + i / 100) * 100 + (i % 100)];
    int row0 = rg * 512;
    for (int rt = 0; rt < 32; rt++) {
        int rbase = row0 + rt * 16;
        __syncthreads();
        for (int i = tid; i < 1600; i += 256) {
            int r = i / 100, d = i % 100;
            us[r * 101 + d] = ws[OFF_U + (size_t)(rbase + r) * 100 + d];
        }
        __syncthreads();
        int r = tid & 15, gl0 = tid >> 4;
        const float* up = us + r * 101;
        for (int gl = gl0; gl < 60; gl += 16) {
            const float* wp = wsl + gl * 100;
            float acc = 0.f;
#pragma unroll 4
            for (int d = 0; d < 100; d++) acc += wp[d] * up[d];
            ws[OFF_P + (size_t)(rbase + r) * 1800 + n * 300 + g0 + gl] = acc;
        }
    }
}

// ---------------------------------------------------------------------------
// Kernel 3: per-batch scan (round-1 structure, float4 weight streams, P-mode)
// 64 blocks x 1024 threads.
// ---------------------------------------------------------------------------
__global__ __launch_bounds__(1024) void scan_kernel(
    const float* __restrict__ hidden, const float* __restrict__ inp_fc_b,
    const float* __restrict__ mha_fc_b, const float* __restrict__ mha_gate_b,
    const float* __restrict__ gru_b_ih, const float* __restrict__ gru_b_hh,
    int use_p, float* __restrict__ ws)
{
    __shared__ float hx[600], gxs[1800], ghs[1800], hns[600];
    __shared__ float qkv[1152], att[160], outv[384];
    __shared__ float gxb[1800], iu[600];
    __shared__ float a0s[8], msk[8], mprev[8];

    int b = blockIdx.x, tid = threadIdx.x;
    const float4* whh4 = (const float4*)(ws + OFF_WHH4);
    const float4* wih4 = (const float4*)(ws + OFF_WIH4);
    const float4* mq4  = (const float4*)(ws + OFF_MQ4);
    const float4* fc4  = (const float4*)(ws + OFF_FC4);
    const float4* gg4  = (const float4*)(ws + OFF_GG4);

    for (int i = tid; i < 600; i += 1024) hx[i] = hidden[b * 600 + i];
    if (use_p) for (int i = tid; i < 1800; i += 1024) gxb[i] = ws[OFF_GXB + i];
    if (tid < 6) mprev[tid] = 1.f;
    __syncthreads();

    for (int t = 0; t < TSTEPS; t++) {
        const float* s1t = ws + OFF_S1 + (size_t)(t * 64 + b) * 600;
        const float* ut  = ws + OFF_U + (size_t)(t * 64 + b) * 100;

        // ---- scores a0[n] = sigmoid(hx_n · s1_n)
        int w = tid >> 6, lane = tid & 63;
        if (w < 6) {
            float p = hx[w * 100 + lane] * s1t[w * 100 + lane];
            if (lane < 36) p += hx[w * 100 + 64 + lane] * s1t[w * 100 + 64 + lane];
#pragma unroll
            for (int off = 32; off > 0; off >>= 1) p += __shfl_down(p, off, 64);
            if (lane == 0) a0s[w] = 1.f / (1.f + expf(-p));
        }
        __syncthreads();

        // ---- top-4 mask (thread 0, overlapped with gx/gh below via divergence)
        if (tid == 0) {
            float sv[6];
            for (int q = 0; q < 6; q++) sv[q] = a0s[q];
            for (int a = 0; a < 5; a++)
                for (int c = a + 1; c < 6; c++)
                    if (sv[c] > sv[a]) { float tm = sv[a]; sv[a] = sv[c]; sv[c] = tm; }
            float kth = sv[3] - 0.01f;
            for (int q = 0; q < 6; q++) msk[q] = (a0s[q] > kth) ? 1.f : 0.f;
        }

        // ---- gx (P-mode: from precomputed P; else build iu first)
        if (use_p) {
            const float4* Pt = (const float4*)(ws + OFF_P + (size_t)(t * 64 + b) * 1800);
            for (int i = tid; i < 450; i += 1024) {
                float4 p4 = Pt[i];
                int i4 = i * 4, n = i4 / 300;
                float a0 = a0s[n];
                gxs[i4]     = a0 * p4.x + gxb[i4];
                gxs[i4 + 1] = a0 * p4.y + gxb[i4 + 1];
                gxs[i4 + 2] = a0 * p4.z + gxb[i4 + 2];
                gxs[i4 + 3] = a0 * p4.w + gxb[i4 + 3];
            }
        } else {
            for (int i = tid; i < 600; i += 1024) {
                int n = i / 100, j = i % 100;
                iu[i] = a0s[n] * ut[j] + inp_fc_b[j];
            }
        }

        // ---- gh: whh stream (float4, coalesced), skip blocks unchanged last step
        for (int i = tid; i < 1800; i += 1024) {
            int n = i / 300, g = i % 300;
            if (mprev[n] != 0.f) {
                const float4* wp = whh4 + n * 7500 + g;
                const float4* h4 = (const float4*)(hx + n * 100);
                float acc = gru_b_hh[n * 300 + g];
#pragma unroll 5
                for (int d4 = 0; d4 < 25; d4++) {
                    float4 wv = wp[d4 * 300];
                    float4 hv = h4[d4];
                    acc += wv.x * hv.x + wv.y * hv.y + wv.z * hv.z + wv.w * hv.w;
                }
                ghs[i] = acc;
            }
        }
        __syncthreads();

        if (!use_p) {   // fallback: gx = wih4 @ iu + b_ih
            for (int i = tid; i < 1800; i += 1024) {
                int n = i / 300, g = i % 300;
                const float4* wp = wih4 + n * 7500 + g;
                const float4* x4 = (const float4*)(iu + n * 100);
                float acc = gru_b_ih[n * 300 + g];
#pragma unroll 5
                for (int d4 = 0; d4 < 25; d4++) {
                    float4 wv = wp[d4 * 300];
                    float4 xv = x4[d4];
                    acc += wv.x * xv.x + wv.y * xv.y + wv.z * xv.z + wv.w * xv.w;
                }
                gxs[i] = acc;
            }
            __syncthreads();
        }

        // ---- GRU combine
        for (int i = tid; i < 600; i += 1024) {
            int n = i / 100, j = i % 100;
            float r  = 1.f / (1.f + expf(-(gxs[n*300 + j]       + ghs[n*300 + j])));
            float z  = 1.f / (1.f + expf(-(gxs[n*300 + 100 + j] + ghs[n*300 + 100 + j])));
            float nn = tanhf(gxs[n*300 + 200 + j] + r * ghs[n*300 + 200 + j]);
            hns[i] = (1.f - z) * nn + z * hx[i];
        }
        __syncthreads();

        // ---- MHA qkv (float4 stream of MQ4)
        for (int o = tid; o < 1152; o += 1024) {
            int n2 = (o % 384) / 64;
            const float4* h4 = (const float4*)(hns + n2 * 100);
            float acc = 0.f;
#pragma unroll 5
            for (int d4 = 0; d4 < 25; d4++) {
                float4 wv = mq4[d4 * 1152 + o];
                float4 hv = h4[d4];
                acc += wv.x * hv.x + wv.y * hv.y + wv.z * hv.z + wv.w * hv.w;
            }
            qkv[o] = acc;
        }
        __syncthreads();

        // ---- attention logits + softmax + attn@V
        if (tid < 144) {
            int h = tid / 36, rem = tid % 36, nq = rem / 6, nk = rem % 6;
            const float* qp = qkv + nq * 64 + h * 16;
            const float* kp = qkv + 384 + nk * 64 + h * 16;
            float acc = 0.f;
#pragma unroll
            for (int d = 0; d < 16; d++) acc += qp[d] * kp[d];
            att[tid] = acc * 0.25f;
        }
        __syncthreads();
        if (tid < 24) {
            int base = tid * 6;
            float m = att[base];
            for (int k2 = 1; k2 < 6; k2++) m = fmaxf(m, att[base + k2]);
            float ssum = 0.f, ex[6];
            for (int k2 = 0; k2 < 6; k2++) { ex[k2] = expf(att[base + k2] - m); ssum += ex[k2]; }
            float inv = 1.f / ssum;
            for (int k2 = 0; k2 < 6; k2++) att[base + k2] = ex[k2] * inv;
        }
        __syncthreads();
        if (tid < 384) {
            int n3 = tid / 64, e = tid % 64, h = e / 16;
            const float* ap = att + h * 36 + n3 * 6;
            float acc = 0.f;
#pragma unroll
            for (int nk = 0; nk < 6; nk++) acc += ap[nk] * qkv[768 + nk * 64 + e];
            outv[tid] = acc;
        }
        __syncthreads();

        // ---- fc/gate (masked blocks only) + hx update + store
        float* og = ws + OFF_OUT + (size_t)(t * 64 + b) * 600;
        for (int i = tid; i < 600; i += 1024) {
            int n = i / 100, j = i % 100;
            float newv;
            if (msk[n] != 0.f) {
                float pj = mha_fc_b[j], gt = mha_gate_b[j];
                const float4* ov4 = (const float4*)(outv + n * 64);
#pragma unroll 4
                for (int e4 = 0; e4 < 16; e4++) {
                    float4 fv = fc4[e4 * 100 + j];
                    float4 gv = gg4[e4 * 100 + j];
                    float4 o4 = ov4[e4];
                    pj += o4.x * fv.x + o4.y * fv.y + o4.z * fv.z + o4.w * fv.w;
                    gt += o4.x * gv.x + o4.y * gv.y + o4.z * gv.z + o4.w * gv.w;
                }
                newv = (1.f / (1.f + expf(-gt))) * tanhf(pj);
            } else {
                newv = hx[i];
            }
            hx[i] = newv;
            og[i] = newv;
        }
        __syncthreads();
        if (tid < 6) mprev[tid] = msk[tid];
        __syncthreads();
    }
}

// ---------------------------------------------------------------------------
// Kernel 4: decode GEMM  C(8192x10000) = A(8192x600) @ W^T + b  (fp32)
// 128x128 tile; per-thread 4+4 split rows/cols (stride-4 LDS = 2-way, free)
// ---------------------------------------------------------------------------
__global__ __launch_bounds__(256) void decode_kernel(
    const float* __restrict__ A, const float* __restrict__ W,
    const float* __restrict__ bias, float* __restrict__ C)
{
    __shared__ float As[8][132];
    __shared__ float Bs[8][132];
    int tid = threadIdx.x;
    int m0 = blockIdx.x * 128;
    int n0 = blockIdx.y * 128;
    int tn = tid % 16, tm = tid / 16;
    int lr = tid / 2, lc = tid % 2;

    float acc[8][8];
#pragma unroll
    for (int i = 0; i < 8; i++)
#pragma unroll
        for (int j = 0; j < 8; j++) acc[i][j] = 0.f;

    for (int k0 = 0; k0 < 600; k0 += 8) {
        float4 av = *(const float4*)(A + (size_t)(m0 + lr) * 600 + k0 + lc * 4);
        float4 bv = make_float4(0.f, 0.f, 0.f, 0.f);
        int wrow = n0 + lr;
        if (wrow < NTOK) bv = *(const float4*)(W + (size_t)wrow * 600 + k0 + lc * 4);
        __syncthreads();
        As[lc*4+0][lr] = av.x; As[lc*4+1][lr] = av.y; As[lc*4+2][lr] = av.z; As[lc*4+3][lr] = av.w;
        Bs[lc*4+0][lr] = bv.x; Bs[lc*4+1][lr] = bv.y; Bs[lc*4+2][lr] = bv.z; Bs[lc*4+3][lr] = bv.w;
        __syncthreads();
#pragma unroll
        for (int kk = 0; kk < 8; kk++) {
            float4 x0 = *(const float4*)&As[kk][tm * 4];
            float4 x1 = *(const float4*)&As[kk][64 + tm * 4];
            float4 y0 = *(const float4*)&Bs[kk][tn * 4];
            float4 y1 = *(const float4*)&Bs[kk][64 + tn * 4];
            float a8[8] = {x0.x, x0.y, x0.z, x0.w, x1.x, x1.y, x1.z, x1.w};
            float b8[8] = {y0.x, y0.y, y0.z, y0.w, y1.x, y1.y, y1.z, y1.w};
#pragma unroll
            for (int i = 0; i < 8; i++)
#pragma unroll
                for (int j = 0; j < 8; j++) acc[i][j] += a8[i] * b8[j];
        }
    }

    int nb0 = n0 + tn * 4, nb1 = n0 + 64 + tn * 4;
    float4 bb0 = make_float4(0.f,0.f,0.f,0.f), bb1 = make_float4(0.f,0.f,0.f,0.f);
    if (nb0 < NTOK) bb0 = *(const float4*)(bias + nb0);
    if (nb1 < NTOK) bb1 = *(const float4*)(bias + nb1);
#pragma unroll
    for (int i = 0; i < 8; i++) {
        int row = m0 + (i < 4 ? tm * 4 + i : 64 + tm * 4 + (i - 4));
        float* crow = C + (size_t)row * NTOK;
        if (nb0 < NTOK) {
            float4 s0 = make_float4(acc[i][0]+bb0.x, acc[i][1]+bb0.y, acc[i][2]+bb0.z, acc[i][3]+bb0.w);
            *(float4*)(crow + nb0) = s0;
        }
        if (nb1 < NTOK) {
            float4 s1v = make_float4(acc[i][4]+bb1.x, acc[i][5]+bb1.y, acc[i][6]+bb1.z, acc[i][7]+bb1.w);
            *(float4*)(crow + nb1) = s1v;
        }
    }
}

// ---------------------------------------------------------------------------
// Kernel 5: hx_final tail + scalar
// ---------------------------------------------------------------------------
__global__ __launch_bounds__(256) void finalize_kernel(
    const float* __restrict__ outp, float* __restrict__ out)
{
    int idx = blockIdx.x * 256 + threadIdx.x;
    if (idx < 38400) out[81920000u + idx] = outp[(size_t)(127 * 64) * 600 + idx];
    if (idx == 38400) out[81958400u] = 0.0f;
}

// ---------------------------------------------------------------------------
extern "C" void kernel_launch(void* const* d_in, const int* in_sizes, int n_in,
                              void* d_out, int out_size, void* d_ws, size_t ws_size,
                              hipStream_t stream)
{
    const int*   input      = (const int*)  d_in[0];
    const float* hidden     = (const float*)d_in[1];
    const float* encoder_w  = (const float*)d_in[2];
    const float* inp_wq     = (const float*)d_in[3];
    const float* inp_wk     = (const float*)d_in[4];
    const float* inp_wv     = (const float*)d_in[5];
    const float* inp_fc_w   = (const float*)d_in[6];
    const float* inp_fc_b   = (const float*)d_in[7];
    const float* mha_wq     = (const float*)d_in[8];
    const float* mha_wk     = (const float*)d_in[9];
    const float* mha_wv     = (const float*)d_in[10];
    const float* mha_fc_w   = (const float*)d_in[11];
    const float* mha_fc_b   = (const float*)d_in[12];
    const float* mha_gate_w = (const float*)d_in[13];
    const float* mha_gate_b = (const float*)d_in[14];
    const float* gru_w_ih   = (const float*)d_in[15];
    const float* gru_w_hh   = (const float*)d_in[16];
    const float* gru_b_ih   = (const float*)d_in[17];
    const float* gru_b_hh   = (const float*)d_in[18];
    const float* dec_w      = (const float*)d_in[19];
    const float* dec_b      = (const float*)d_in[20];
    float* out = (float*)d_out;
    float* ws  = (float*)d_ws;

    int use_p = (ws_size >= TOTAL_WITH_P * 4ull) ? 1 : 0;

    transpose_kernel<<<256, 256, 0, stream>>>(inp_wq, inp_fc_w, inp_fc_b,
                                              mha_fc_w, mha_gate_w,
                                              mha_wq, mha_wk, mha_wv,
                                              gru_w_ih, gru_w_hh, gru_b_ih, ws);
    precompute_kernel<<<512, 256, 0, stream>>>(input, encoder_w, inp_wk, inp_wv, ws);
    if (use_p)
        pgate_kernel<<<480, 256, 0, stream>>>(gru_w_ih, ws);
    scan_kernel<<<64, 1024, 0, stream>>>(hidden, inp_fc_b, mha_fc_b, mha_gate_b,
                                         gru_b_ih, gru_b_hh, use_p, ws);
    decode_kernel<<<dim3(64, 79), dim3(256), 0, stream>>>(ws + OFF_OUT, dec_w, dec_b, out);
    finalize_kernel<<<151, 256, 0, stream>>>(ws + OFF_OUT, out);
}